// Round 7
// baseline (5099.378 us; speedup 1.0000x reference)
//
#include <hip/hip_runtime.h>
#include <hip/hip_bf16.h>

typedef short s8v __attribute__((ext_vector_type(8)));   // 8 bf16 (4 VGPRs) MFMA frag
typedef float f4v __attribute__((ext_vector_type(4)));   // MFMA accum frag / float4 load

#define NBLK 256   // 8 XCD-stage slots * 32 slices (stages 6,7 idle)
#define HDEPTH 32  // h-history ring depth (WAR backpressure slack)

typedef unsigned short u16;
typedef unsigned long long u64;

__device__ __forceinline__ float b2f(u16 u) {
  union { unsigned int i; float f; } v; v.i = ((unsigned int)u) << 16; return v.f;
}
__device__ __forceinline__ u16 f2b(float f) {
  union { float f; unsigned int i; } v; v.f = f;
  unsigned int x = v.i;
  return (u16)((x + 0x7fffu + ((x >> 16) & 1u)) >> 16);  // RNE
}
__device__ __forceinline__ s8v cvt8(f4v a, f4v b) {
  s8v r;
  r[0] = (short)f2b(a[0]); r[1] = (short)f2b(a[1]);
  r[2] = (short)f2b(a[2]); r[3] = (short)f2b(a[3]);
  r[4] = (short)f2b(b[0]); r[5] = (short)f2b(b[1]);
  r[6] = (short)f2b(b[2]); r[7] = (short)f2b(b[3]);
  return r;
}

// sc0 load: bypass L1, served by the local XCD L2 (fresh w.r.t. same-XCD plain
// stores, no atomic-RMW bank serialization).  Poll-loop use only.
__device__ __forceinline__ unsigned ld_l2(const unsigned* p) {
  unsigned v;
  asm volatile("global_load_dword %0, %1, off sc0" : "=v"(v) : "v"(p) : "memory");
  asm volatile("s_waitcnt vmcnt(0)" ::: "memory");
  return v;
}

// ---------------------------------------------------------------------------
// P1: build transposed bf16 weights from float32 sources.
// WT[stage][col 0..2047][k 0..1023] (bf16), stage = d*3+l:
//   l==0 : k<512 -> rec[d][0][k][col];  k-512 in [0,300) -> k0[d][k-512][col]; else 0
//   l>=1 : k<512 -> k12[d][l-1][k][col]; else rec[d][l][k-512][col]
// WaT[n][k] = Wa0[k][n];  WdT likewise for Wd0.
// ---------------------------------------------------------------------------
__global__ __launch_bounds__(256) void prep_weights(
    const float* __restrict__ k0, const float* __restrict__ k12,
    const float* __restrict__ rec, const float* __restrict__ Wa0,
    const float* __restrict__ Wd0,
    u16* __restrict__ WT, u16* __restrict__ WaT, u16* __restrict__ WdT)
{
  __shared__ u16 tl[64][65];
  int bid = blockIdx.x, tid = threadIdx.x;
  if (bid < 3072) {
    int stage = bid >> 9;
    int t2 = bid & 511;
    int ct = t2 >> 4, kt = t2 & 15;
    int d = stage / 3, l = stage - 3 * d;
    int colbase = ct * 64, kbase = kt * 64;
    int cl = tid & 63;
#pragma unroll
    for (int i = 0; i < 16; ++i) {
      int kl = i * 4 + (tid >> 6);
      int k = kbase + kl, col = colbase + cl;
      float v;
      if (l == 0) {
        if (k < 512) v = rec[((size_t)(d * 3 + 0) * 512 + k) * 2048 + col];
        else { int j = k - 512; v = (j < 300) ? k0[((size_t)d * 300 + j) * 2048 + col] : 0.f; }
      } else {
        if (k < 512) v = k12[((size_t)(d * 2 + (l - 1)) * 512 + k) * 2048 + col];
        else         v = rec[((size_t)(d * 3 + l) * 512 + (k - 512)) * 2048 + col];
      }
      tl[kl][cl] = f2b(v);
    }
    __syncthreads();
#pragma unroll
    for (int i = 0; i < 16; ++i) {
      int cl2 = i * 4 + (tid >> 6);
      int kl2 = tid & 63;
      WT[((size_t)stage * 2048 + colbase + cl2) * 1024 + kbase + kl2] = tl[kl2][cl2];
    }
  } else {
    int m = bid - 3072;
    int mat = m >> 5, tt = m & 31;
    int nt = tt & 3, kt = tt >> 2;
    const float* src = mat ? Wd0 : Wa0;
    u16* dst = mat ? WdT : WaT;
    int nbase = nt * 64, kbase = kt * 64;
    int cl = tid & 63;
#pragma unroll
    for (int i = 0; i < 16; ++i) {
      int kl = i * 4 + (tid >> 6);
      tl[kl][cl] = f2b(src[(size_t)(kbase + kl) * 256 + nbase + cl]);
    }
    __syncthreads();
#pragma unroll
    for (int i = 0; i < 16; ++i) {
      int nl = i * 4 + (tid >> 6);
      int kl = tid & 63;
      dst[(size_t)(nbase + nl) * 512 + kbase + kl] = tl[kl][nl];
    }
  }
}

// ---------------------------------------------------------------------------
// Main persistent LSTM kernel.  256 blocks, XCD-AFFINITY MAPPING (R4):
//   stage = bid & 7 (bid%8 -> XCD), slice = bid >> 3; stages 6,7 exit early.
// SYNC (R6, kept): plain-store publish to local mirror + sc0-load poll;
//   master (MALL, agent) flags for producer check + WAR + every-8th-iter
//   fallback merge (placement safety: mirror stale-low -> master rescues).
// COMPUTE (R7): depth-2 SOFTWARE PIPELINE on the load batches.
//   R6 proved the period was load-latency-serialized (batching 8 loads/round
//   was -31%).  The 4 m-tile rounds (h-path) and 8 rounds (emb path) are
//   fully independent -> ping-pong named batches (avA/avB, fA/fB; rule-#20
//   safe: no runtime indexing) so batch mt+1's loads issue while batch mt's
//   MFMAs execute; compiler emits counted vmcnt(8) waits.  w==3 hoists all
//   loads upfront.  Hides all but one round-trip per step.
// h ring layout: [slot][stage][slice-tile 0..31][row 0..63][16 units];
//   agent-scope 8B write-through stores (contiguous 2KB tile); plain cached
//   consumer loads kept fresh by ring depth 32 + staggered acquire fence
//   every 8 steps (staleness bound 8 < 32).
// out3 ALIASES WT (dead after prologue counter-barrier).
// ---------------------------------------------------------------------------
__global__ __launch_bounds__(256, 1) void lstm_main(
    const u16* __restrict__ WT, const float* __restrict__ emb,
    const int* __restrict__ ids, const float* __restrict__ bias,
    u16* __restrict__ hist, const u16* __restrict__ zbuf,
    u16* __restrict__ out3, unsigned* __restrict__ bar)
{
  __shared__ float lpart[4][48][68];   // [src wave][3 m-tiles *16][64 cols+pad]
  __shared__ __align__(16) u16 hs[64][20];  // h repack tile, padded row (40B) vs bank conflicts
  const int tid = threadIdx.x;
  const int w = tid >> 6;            // wave id (K-split, and cell-update row group)
  const int lane = tid & 63;
  const int lm = lane & 15, qk = lane >> 4;
  const int bid = blockIdx.x;
  const int stage = bid & 7;         // XCD affinity: bid%8 -> XCD
  const int slice = bid >> 3;        // 0..31
  const int u0 = slice * 16;

  // One-time barrier: all B-frag reads complete before out3 tramples WT.
  // (idle stage-slots participate, then exit)
  if (stage >= 6) {
    __syncthreads();
    if (tid == 0) {
      __hip_atomic_fetch_add(bar, 1u, __ATOMIC_RELAXED, __HIP_MEMORY_SCOPE_AGENT);
      while (__hip_atomic_load(bar, __ATOMIC_RELAXED, __HIP_MEMORY_SCOPE_AGENT) < (unsigned)NBLK)
        __builtin_amdgcn_s_sleep(2);
    }
    __syncthreads();
    return;
  }

  const int d = stage / 3, l = stage - 3 * d;

  unsigned* flags = bar + 16;                       // 6*32 master words (MALL)
  unsigned* fO = flags + stage * 32;
  unsigned* fP = flags + (l > 0 ? (stage - 1) : stage) * 32;
  unsigned* fC = flags + (l < 2 ? (stage + 1) : stage) * 32;
  unsigned* myf = fO + slice;
  unsigned* mirS = bar + 256 + stage * 32;          // per-stage LOCAL mirror (XCD L2)

  // B fragments: col = nt*512 + u0 + lm (gate nt), k = w*256 + ks*32 + qk*8
  s8v bfr[8][4];
#pragma unroll
  for (int ks = 0; ks < 8; ++ks)
#pragma unroll
    for (int nt = 0; nt < 4; ++nt)
      bfr[ks][nt] = *(const s8v*)(WT + ((size_t)stage * 2048 + nt * 512 + u0 + lm) * 1024
                                  + w * 256 + ks * 32 + qk * 8);
  float bias4[4];
#pragma unroll
  for (int nt = 0; nt < 4; ++nt)
    bias4[nt] = bias[((size_t)d * 3 + l) * 2048 + nt * 512 + u0 + lm];

  float c[4] = {0.f, 0.f, 0.f, 0.f};      // cell state, rows 16w+qk*4+r, unit u0+lm
  const int brow = 16 * w + qk * 4;
  const f4v fzero = {0.f, 0.f, 0.f, 0.f};

  // h-load addressing constants for the tiled layout:
  // element k of a row lives at tile (k>>4), elem offset row*16 + (k&15).
  const int kc = (qk & 1) * 8;               // within-tile elem of this lane's 8-elem run
  const int slq = qk >> 1;                   // tile contribution of qk

  __syncthreads();
  if (tid == 0) {
    __hip_atomic_fetch_add(bar, 1u, __ATOMIC_RELAXED, __HIP_MEMORY_SCOPE_AGENT);
    while (__hip_atomic_load(bar, __ATOMIC_RELAXED, __HIP_MEMORY_SCOPE_AGENT) < (unsigned)NBLK)
      __builtin_amdgcn_s_sleep(2);
  }
  __syncthreads();

  for (int s = 0; s < 258; ++s) {
    // ---- dependency wait ----
    if (w == 0) {
      const unsigned sU = (unsigned)s;
      if (l < 2 && (s & 7) == 0) {
        // WAR backpressure: consumer must be within 24 steps (covers s..s+7 vs ring 32)
        for (;;) {
          bool ok = true;
          if (lane < 32) {
            int vC = (int)__hip_atomic_load(fC + lane, __ATOMIC_RELAXED, __HIP_MEMORY_SCOPE_AGENT);
            ok = (vC >= s - 24);
          }
          if (__all(ok)) break;
          __builtin_amdgcn_s_sleep(2);
        }
      }
      unsigned it = 0;
      for (;;) {
        bool ok = true;
        if (lane < 32) {
          unsigned v = ld_l2(mirS + lane);
          if (v < sU && (it & 7) == 7) {
            unsigned vm = __hip_atomic_load(fO + lane, __ATOMIC_RELAXED, __HIP_MEMORY_SCOPE_AGENT);
            if (vm > v) v = vm;
          }
          ok = (v >= sU);
        } else if (l > 0) {
          unsigned v = __hip_atomic_load(fP + (lane - 32), __ATOMIC_RELAXED, __HIP_MEMORY_SCOPE_AGENT);
          ok = (v >= sU);
        }
        if (__all(ok)) break;
        ++it;
        __builtin_amdgcn_s_sleep(1);
      }
      if (tid == 0 && ((s + stage) & 7) == 7)
        __builtin_amdgcn_fence(__ATOMIC_ACQUIRE, "agent");  // staggered inv: staleness <=8 < 32
    }
    __syncthreads();

    int t = s - l;
    if (t >= 0 && t < 256) {
      int tx = d ? (255 - t) : t;        // time index into input sequence
      const u16* lo;
      const u16* hi;
      if (l == 0) {
        lo = (t == 0) ? zbuf
             : hist + ((size_t)((t - 1) & (HDEPTH - 1)) * 6 + stage) * 32768;      // h1[t-1]
        hi = lo;                                                  // unused (emb path)
      } else {
        lo = hist + ((size_t)(t & (HDEPTH - 1)) * 6 + (stage - 1)) * 32768;        // h_{l-1}[t]
        hi = (t == 0) ? zbuf
             : hist + ((size_t)((t - 1) & (HDEPTH - 1)) * 6 + stage) * 32768;      // h_l[t-1]
      }

      f4v acc[4][4];
#pragma unroll
      for (int mt = 0; mt < 4; ++mt)
#pragma unroll
        for (int nt = 0; nt < 4; ++nt) acc[mt][nt] = fzero;

      if (l == 0 && w >= 2) {
        // ---- input-projection side: A = emb[ids[row][tx]] (float row, 16B aligned) ----
        int idv[4];
#pragma unroll
        for (int mt = 0; mt < 4; ++mt) idv[mt] = ids[(mt * 16 + lm) * 256 + tx];
        if (w == 2) {                    // j in [0,256): depth-2 pipelined 8 rounds
#define ELOAD(F, MT, H2) { \
  const float* er_ = emb + (size_t)idv[MT] * 300; \
  _Pragma("unroll") for (int j = 0; j < 4; ++j) { \
    F[2*j]   = *(const f4v*)(er_ + ((H2)*4 + j)*32 + qk*8); \
    F[2*j+1] = *(const f4v*)(er_ + ((H2)*4 + j)*32 + qk*8 + 4); } }
#define EMFMA(F, MT, H2) { \
  _Pragma("unroll") for (int j = 0; j < 4; ++j) { \
    s8v a_ = cvt8(F[2*j], F[2*j+1]); \
    _Pragma("unroll") for (int nt = 0; nt < 4; ++nt) \
      acc[MT][nt] = __builtin_amdgcn_mfma_f32_16x16x32_bf16(a_, bfr[(H2)*4 + j][nt], acc[MT][nt], 0, 0, 0); } }
          f4v fA[8], fB[8];
          ELOAD(fA, 0, 0); ELOAD(fB, 0, 1);
          EMFMA(fA, 0, 0); ELOAD(fA, 1, 0);
          EMFMA(fB, 0, 1); ELOAD(fB, 1, 1);
          EMFMA(fA, 1, 0); ELOAD(fA, 2, 0);
          EMFMA(fB, 1, 1); ELOAD(fB, 2, 1);
          EMFMA(fA, 2, 0); ELOAD(fA, 3, 0);
          EMFMA(fB, 2, 1); ELOAD(fB, 3, 1);
          EMFMA(fA, 3, 0);
          EMFMA(fB, 3, 1);
#undef ELOAD
#undef EMFMA
        } else {                         // w==3: j in [256,512); hoist ALL loads upfront
          f4v e0[4], e1[4], e2[4], e3[4];
#pragma unroll
          for (int mt = 0; mt < 4; ++mt) {
            const float* er = emb + (size_t)idv[mt] * 300;
            e0[mt] = *(const f4v*)(er + 256 + qk * 8);       // ks=0: j 256..287
            e1[mt] = *(const f4v*)(er + 256 + qk * 8 + 4);
            if (qk == 0)      { e2[mt] = *(const f4v*)(er + 288); e3[mt] = *(const f4v*)(er + 292); }
            else if (qk == 1) { e2[mt] = *(const f4v*)(er + 296); e3[mt] = fzero; }
            else              { e2[mt] = fzero; e3[mt] = fzero; }   // j>=304: WT rows zero
          }
#pragma unroll
          for (int mt = 0; mt < 4; ++mt) {
            s8v a0 = cvt8(e0[mt], e1[mt]);
#pragma unroll
            for (int nt = 0; nt < 4; ++nt)
              acc[mt][nt] = __builtin_amdgcn_mfma_f32_16x16x32_bf16(a0, bfr[0][nt], acc[mt][nt], 0, 0, 0);
            s8v a1 = cvt8(e2[mt], e3[mt]);
#pragma unroll
            for (int nt = 0; nt < 4; ++nt)
              acc[mt][nt] = __builtin_amdgcn_mfma_f32_16x16x32_bf16(a1, bfr[1][nt], acc[mt][nt], 0, 0, 0);
            // ks 2..7 contribute zero (WT rows >= 832 are 0): skipped
          }
        }
      } else {
        // ---- standard h-side path: depth-2 pipelined m-tile batches ----
        const u16* aptr = (w < 2) ? lo : hi;
        const int slb = ((w & 1) * 16) + slq;      // tile index base: koff/16 + qk/2
#define HLOAD(AV, MT) { \
  _Pragma("unroll") for (int ks = 0; ks < 8; ++ks) \
    AV[ks] = *(const s8v*)(aptr + (size_t)(slb + 2*ks)*1024 + ((MT)*16 + lm)*16 + kc); }
#define HMFMA(AV, MT) { \
  _Pragma("unroll") for (int ks = 0; ks < 8; ++ks) \
    _Pragma("unroll") for (int nt = 0; nt < 4; ++nt) \
      acc[MT][nt] = __builtin_amdgcn_mfma_f32_16x16x32_bf16(AV[ks], bfr[ks][nt], acc[MT][nt], 0, 0, 0); }
        s8v avA[8], avB[8];
        HLOAD(avA, 0); HLOAD(avB, 1);
        HMFMA(avA, 0); HLOAD(avA, 2);
        HMFMA(avB, 1); HLOAD(avB, 3);
        HMFMA(avA, 2);
        HMFMA(avB, 3);
#undef HLOAD
#undef HMFMA
      }

      // cross-wave K reduction: wave w keeps m-tile w, ships the other three
#pragma unroll
      for (int mt = 0; mt < 4; ++mt) {
        if (mt == w) continue;
        int slot = mt - (mt > w ? 1 : 0);
#pragma unroll
        for (int nt = 0; nt < 4; ++nt)
#pragma unroll
          for (int r = 0; r < 4; ++r)
            lpart[w][slot * 16 + qk * 4 + r][nt * 16 + lm] = acc[mt][nt][r];
      }
      __syncthreads();

      float z[4][4];
#pragma unroll
      for (int nt = 0; nt < 4; ++nt)
#pragma unroll
        for (int r = 0; r < 4; ++r) {
          float v = acc[w][nt][r];
#pragma unroll
          for (int ps = 0; ps < 4; ++ps) {
            if (ps == w) continue;
            int slot = w - (w > ps ? 1 : 0);
            v += lpart[ps][slot * 16 + qk * 4 + r][nt * 16 + lm];
          }
          z[nt][r] = v + bias4[nt];
        }

      // cell update: i,f,g,o = z[0..3]; stage h into LDS for wide stores
#pragma unroll
      for (int r = 0; r < 4; ++r) {
        float zi = z[0][r], zf = z[1][r], zg = z[2][r], zo = z[3][r];
        float si = 1.f / (1.f + __expf(-zi));
        float sf = 1.f / (1.f + __expf(-zf));
        float so = 1.f / (1.f + __expf(-zo));
        float sg = zg / (1.f + fabsf(zg));
        float cn = sf * c[r] + si * sg;
        c[r] = cn;
        float h = so * (cn / (1.f + fabsf(cn)));
        hs[brow + r][lm] = f2b(h);
      }
      __syncthreads();

      // cooperative write-through to MALL: 256 threads x 8B agent-scope stores,
      // fully contiguous 2KB tile -> 32 complete 64B lines, fast vmcnt drain.
      u16* hq = hist + ((size_t)(t & (HDEPTH - 1)) * 6 + stage) * 32768
                     + (size_t)slice * 1024;
      int row = tid >> 2, part = tid & 3;
      u64 v8 = *(const u64*)&hs[row][part * 4];
      __hip_atomic_store((u64*)(hq + tid * 4), v8, __ATOMIC_RELAXED, __HIP_MEMORY_SCOPE_AGENT);
      if (l == 2)
        *(u64*)(out3 + ((size_t)d * 256 + t) * 64 * 512
                + (size_t)row * 512 + u0 + part * 4) = v8;  // plain cached store
    }
    __syncthreads();   // drain all stores (vmcnt(0) per wave) before publishing
    if (tid == 0) {
      __hip_atomic_store(mirS + slice, (unsigned)(s + 1),
                         __ATOMIC_RELAXED, __HIP_MEMORY_SCOPE_WORKGROUP);  // plain -> local L2
      __hip_atomic_store(myf, (unsigned)(s + 1),
                         __ATOMIC_RELAXED, __HIP_MEMORY_SCOPE_AGENT);      // MALL master
    }
  }
}

// ---------------------------------------------------------------------------
// Attention scores: per t-block, enc = 0.5*(out3[0][t]+out3[1][t]) on the fly,
// a = prelu(enc@Wa0+ba0), scores[b][t] = a@Wa1 + ba1.
// ---------------------------------------------------------------------------
__global__ __launch_bounds__(256) void attn_scores(
    const u16* __restrict__ out3, const u16* __restrict__ WaT,
    const float* __restrict__ ba0, const float* __restrict__ alpha_a,
    const float* __restrict__ Wa1, const float* __restrict__ ba1,
    float* __restrict__ scores)
{
  int t = blockIdx.x, tid = threadIdx.x;
  int w = tid >> 6, lane = tid & 63, lm = lane & 15, qk = lane >> 4;
  const u16* e0 = out3 + (size_t)t * 64 * 512;
  const u16* e1 = out3 + ((size_t)256 + t) * 64 * 512;
  const f4v fzero = {0.f, 0.f, 0.f, 0.f};
  f4v acc[16];
#pragma unroll
  for (int nt = 0; nt < 16; ++nt) acc[nt] = fzero;

  for (int ks = 0; ks < 16; ++ks) {
    size_t aoff = (size_t)(16 * w + lm) * 512 + ks * 32 + qk * 8;
    s8v a0 = *(const s8v*)(e0 + aoff);
    s8v a1 = *(const s8v*)(e1 + aoff);
    s8v af;
#pragma unroll
    for (int j = 0; j < 8; ++j)
      af[j] = (short)f2b(0.5f * (b2f((u16)a0[j]) + b2f((u16)a1[j])));
#pragma unroll
    for (int nt = 0; nt < 16; ++nt) {
      s8v bf = *(const s8v*)(WaT + (size_t)(nt * 16 + lm) * 512 + ks * 32 + qk * 8);
      acc[nt] = __builtin_amdgcn_mfma_f32_16x16x32_bf16(af, bf, acc[nt], 0, 0, 0);
    }
  }

  float sums[4] = {0.f, 0.f, 0.f, 0.f};
#pragma unroll
  for (int nt = 0; nt < 16; ++nt) {
    int col = nt * 16 + lm;
    float bb = ba0[col];
    float al = alpha_a[col];
    float wv = Wa1[col];
#pragma unroll
    for (int r = 0; r < 4; ++r) {
      float v = acc[nt][r] + bb;
      v = (v >= 0.f) ? v : al * v;
      sums[r] += v * wv;
    }
  }
  float bb1 = ba1[0];
#pragma unroll
  for (int r = 0; r < 4; ++r) {
    float v = sums[r];
    v += __shfl_xor(v, 1, 16);
    v += __shfl_xor(v, 2, 16);
    v += __shfl_xor(v, 4, 16);
    v += __shfl_xor(v, 8, 16);
    if (lm == 0) {
      int b = 16 * w + qk * 4 + r;
      scores[(size_t)b * 256 + t] = v + bb1;
    }
  }
}

// ---------------------------------------------------------------------------
// Softmax over T + pooled[b][u] = sum_t w[t]*enc[b][t][u]
// ---------------------------------------------------------------------------
__global__ __launch_bounds__(256) void attn_pool(
    const u16* __restrict__ out3, const float* __restrict__ scores,
    u16* __restrict__ pooled)
{
  __shared__ float red[256];
  __shared__ float wts[256];
  int b = blockIdx.x, tid = threadIdx.x;
  float s = scores[(size_t)b * 256 + tid];
  red[tid] = s; __syncthreads();
  for (int o = 128; o > 0; o >>= 1) { if (tid < o) red[tid] = fmaxf(red[tid], red[tid + o]); __syncthreads(); }
  float m = red[0]; __syncthreads();
  float e = __expf(s - m);
  red[tid] = e; __syncthreads();
  for (int o = 128; o > 0; o >>= 1) { if (tid < o) red[tid] += red[tid + o]; __syncthreads(); }
  float inv = 1.f / red[0];
  wts[tid] = e * inv; __syncthreads();

  int u2 = tid * 2;
  float a0 = 0.f, a1 = 0.f;
#pragma unroll 4
  for (int t = 0; t < 256; ++t) {
    float wt = wts[t];
    const ushort2 v0 = *(const ushort2*)(out3 + ((size_t)t * 64 + b) * 512 + u2);
    const ushort2 v1 = *(const ushort2*)(out3 + (((size_t)256 + t) * 64 + b) * 512 + u2);
    a0 += wt * 0.5f * (b2f(v0.x) + b2f(v1.x));
    a1 += wt * 0.5f * (b2f(v0.y) + b2f(v1.y));
  }
  pooled[(size_t)b * 512 + u2] = f2b(a0);
  pooled[(size_t)b * 512 + u2 + 1] = f2b(a1);
}

// ---------------------------------------------------------------------------
// Head: h = prelu(BN(pooled@Wd0+bd0)); out = softmax(h@Wd1+bd1)  (float out)
// ---------------------------------------------------------------------------
__global__ __launch_bounds__(256) void head(
    const u16* __restrict__ pooled, const u16* __restrict__ WdT,
    const float* __restrict__ bd0, const float* __restrict__ gamma,
    const float* __restrict__ beta, const float* __restrict__ bn_mean,
    const float* __restrict__ bn_var, const float* __restrict__ alpha_h,
    const float* __restrict__ Wd1, const float* __restrict__ bd1,
    float* __restrict__ outp)
{
  __shared__ float hl[64][260];
  __shared__ float lg[64][8];
  int tid = threadIdx.x;
  int w = tid >> 6, lane = tid & 63, lm = lane & 15, qk = lane >> 4;
  const f4v fzero = {0.f, 0.f, 0.f, 0.f};
  f4v acc[16];
#pragma unroll
  for (int nt = 0; nt < 16; ++nt) acc[nt] = fzero;
  for (int ks = 0; ks < 16; ++ks) {
    s8v a = *(const s8v*)(pooled + (size_t)(16 * w + lm) * 512 + ks * 32 + qk * 8);
#pragma unroll
    for (int nt = 0; nt < 16; ++nt) {
      s8v bf = *(const s8v*)(WdT + (size_t)(nt * 16 + lm) * 512 + ks * 32 + qk * 8);
      acc[nt] = __builtin_amdgcn_mfma_f32_16x16x32_bf16(a, bf, acc[nt], 0, 0, 0);
    }
  }
#pragma unroll
  for (int nt = 0; nt < 16; ++nt) {
    int col = nt * 16 + lm;
    float mn = bn_mean[col];
    float sc = gamma[col] * rsqrtf(bn_var[col] + 1e-3f);
    float be = beta[col];
    float al = alpha_h[col];
    float b0 = bd0[col];
#pragma unroll
    for (int r = 0; r < 4; ++r) {
      float v = acc[nt][r] + b0;
      v = (v - mn) * sc + be;
      v = (v >= 0.f) ? v : al * v;
      hl[16 * w + qk * 4 + r][col] = v;
    }
  }
  __syncthreads();
  for (int idx = tid; idx < 448; idx += 256) {
    int b = idx / 7, cc = idx - b * 7;
    float sv = bd1[cc];
    for (int k = 0; k < 256; ++k) sv += hl[b][k] * Wd1[k * 7 + cc];
    lg[b][cc] = sv;
  }
  __syncthreads();
  if (tid < 64) {
    float mx = -1e30f;
#pragma unroll
    for (int cc = 0; cc < 7; ++cc) mx = fmaxf(mx, lg[tid][cc]);
    float sum = 0.f; float ex[7];
#pragma unroll
    for (int cc = 0; cc < 7; ++cc) { ex[cc] = __expf(lg[tid][cc] - mx); sum += ex[cc]; }
    float inv = 1.f / sum;
#pragma unroll
    for (int cc = 0; cc < 7; ++cc) outp[tid * 7 + cc] = ex[cc] * inv;
  }
}

// ---------------------------------------------------------------------------
extern "C" void kernel_launch(void* const* d_in, const int* in_sizes, int n_in,
                              void* d_out, int out_size, void* d_ws, size_t ws_size,
                              hipStream_t stream)
{
  (void)in_sizes; (void)n_in; (void)out_size; (void)ws_size;
  const int*   ids     = (const int*)d_in[0];
  const float* emb     = (const float*)d_in[1];
  const float* k0      = (const float*)d_in[2];
  const float* k12     = (const float*)d_in[3];
  const float* rec     = (const float*)d_in[4];
  const float* bias    = (const float*)d_in[5];
  const float* Wa0     = (const float*)d_in[6];
  const float* ba0     = (const float*)d_in[7];
  const float* alpha_a = (const float*)d_in[8];
  const float* Wa1     = (const float*)d_in[9];
  const float* ba1     = (const float*)d_in[10];
  const float* Wd0     = (const float*)d_in[11];
  const float* bd0     = (const float*)d_in[12];
  const float* gamma   = (const float*)d_in[13];
  const float* beta    = (const float*)d_in[14];
  const float* bn_mean = (const float*)d_in[15];
  const float* bn_var  = (const float*)d_in[16];
  const float* alpha_h = (const float*)d_in[17];
  const float* Wd1     = (const float*)d_in[18];
  const float* bd1     = (const float*)d_in[19];

  char* ws = (char*)d_ws;
  // out3 (33,554,432 B) ALIASES WT (25,165,824 B): WT is dead once lstm_main's
  // prologue barrier passes (B-frags register-resident); out3 writes start after.
  u16* WT      = (u16*)(ws);                    // [0, 25.17 MB)
  u16* out3    = (u16*)(ws);                    // [0, 33.55 MB)
  u16* hist    = (u16*)(ws + 33554432);         // 32*6*32*1024*2 = 12,582,912
  u16* WaT     = (u16*)(ws + 46137344);         // 262,144
  u16* WdT     = (u16*)(ws + 46399488);         // 262,144
  float* scores= (float*)(ws + 46661632);       // 65,536
  u16* pooled  = (u16*)(ws + 46727168);         // 65,536
  u16* zbuf    = (u16*)(ws + 46792704);         // 65,536 (zero tile)
  unsigned* bar= (unsigned*)(ws + 46858240);    // [0]=prologue counter, +16: 192 master
                                                // flags, +256: 192 local-mirror flags
                                                // total 46,860,288 B

  hipMemsetAsync(zbuf, 0, 65536, stream);
  hipMemsetAsync(bar, 0, 2048, stream);

  prep_weights<<<dim3(3136), dim3(256), 0, stream>>>(k0, k12, rec, Wa0, Wd0, WT, WaT, WdT);

  void* args[] = { (void*)&WT, (void*)&emb, (void*)&ids, (void*)&bias,
                   (void*)&hist, (void*)&zbuf, (void*)&out3, (void*)&bar };
  hipLaunchCooperativeKernel((void*)lstm_main, dim3(NBLK), dim3(256), args, 0, stream);

  attn_scores<<<dim3(256), dim3(256), 0, stream>>>(out3, WaT, ba0, alpha_a, Wa1, ba1, scores);
  attn_pool<<<dim3(64), dim3(256), 0, stream>>>(out3, scores, pooled);
  head<<<dim3(1), dim3(256), 0, stream>>>(pooled, WdT, bd0, gamma, beta, bn_mean, bn_var,
                                          alpha_h, Wd1, bd1, (float*)d_out);
}

// Round 8
// 3255.676 us; speedup vs baseline: 1.5663x; 1.5663x over previous
//
#include <hip/hip_runtime.h>
#include <hip/hip_bf16.h>

typedef short s8v __attribute__((ext_vector_type(8)));   // 8 bf16 (4 VGPRs) MFMA frag
typedef float f4v __attribute__((ext_vector_type(4)));   // MFMA accum frag / float4 load

#define NBLK 256   // 8 XCD-stage slots * 32 slices (stages 6,7 idle)
#define HDEPTH 32  // h-history ring depth (WAR backpressure slack)

typedef unsigned short u16;
typedef unsigned long long u64;

__device__ __forceinline__ float b2f(u16 u) {
  union { unsigned int i; float f; } v; v.i = ((unsigned int)u) << 16; return v.f;
}
__device__ __forceinline__ u16 f2b(float f) {
  union { float f; unsigned int i; } v; v.f = f;
  unsigned int x = v.i;
  return (u16)((x + 0x7fffu + ((x >> 16) & 1u)) >> 16);  // RNE
}
__device__ __forceinline__ s8v cvt8(f4v a, f4v b) {
  s8v r;
  r[0] = (short)f2b(a[0]); r[1] = (short)f2b(a[1]);
  r[2] = (short)f2b(a[2]); r[3] = (short)f2b(a[3]);
  r[4] = (short)f2b(b[0]); r[5] = (short)f2b(b[1]);
  r[6] = (short)f2b(b[2]); r[7] = (short)f2b(b[3]);
  return r;
}

// sc0 load: bypass L1, served by the local XCD L2 (fresh w.r.t. same-XCD plain
// stores, no atomic-RMW bank serialization).  Poll-loop use only.
__device__ __forceinline__ unsigned ld_l2(const unsigned* p) {
  unsigned v;
  asm volatile("global_load_dword %0, %1, off sc0" : "=v"(v) : "v"(p) : "memory");
  asm volatile("s_waitcnt vmcnt(0)" ::: "memory");
  return v;
}

// ---------------------------------------------------------------------------
// P1: build transposed bf16 weights from float32 sources.
// WT[stage][col 0..2047][k 0..1023] (bf16), stage = d*3+l:
//   l==0 : k<512 -> rec[d][0][k][col];  k-512 in [0,300) -> k0[d][k-512][col]; else 0
//   l>=1 : k<512 -> k12[d][l-1][k][col]; else rec[d][l][k-512][col]
// WaT[n][k] = Wa0[k][n];  WdT likewise for Wd0.
// ---------------------------------------------------------------------------
__global__ __launch_bounds__(256) void prep_weights(
    const float* __restrict__ k0, const float* __restrict__ k12,
    const float* __restrict__ rec, const float* __restrict__ Wa0,
    const float* __restrict__ Wd0,
    u16* __restrict__ WT, u16* __restrict__ WaT, u16* __restrict__ WdT)
{
  __shared__ u16 tl[64][65];
  int bid = blockIdx.x, tid = threadIdx.x;
  if (bid < 3072) {
    int stage = bid >> 9;
    int t2 = bid & 511;
    int ct = t2 >> 4, kt = t2 & 15;
    int d = stage / 3, l = stage - 3 * d;
    int colbase = ct * 64, kbase = kt * 64;
    int cl = tid & 63;
#pragma unroll
    for (int i = 0; i < 16; ++i) {
      int kl = i * 4 + (tid >> 6);
      int k = kbase + kl, col = colbase + cl;
      float v;
      if (l == 0) {
        if (k < 512) v = rec[((size_t)(d * 3 + 0) * 512 + k) * 2048 + col];
        else { int j = k - 512; v = (j < 300) ? k0[((size_t)d * 300 + j) * 2048 + col] : 0.f; }
      } else {
        if (k < 512) v = k12[((size_t)(d * 2 + (l - 1)) * 512 + k) * 2048 + col];
        else         v = rec[((size_t)(d * 3 + l) * 512 + (k - 512)) * 2048 + col];
      }
      tl[kl][cl] = f2b(v);
    }
    __syncthreads();
#pragma unroll
    for (int i = 0; i < 16; ++i) {
      int cl2 = i * 4 + (tid >> 6);
      int kl2 = tid & 63;
      WT[((size_t)stage * 2048 + colbase + cl2) * 1024 + kbase + kl2] = tl[kl2][cl2];
    }
  } else {
    int m = bid - 3072;
    int mat = m >> 5, tt = m & 31;
    int nt = tt & 3, kt = tt >> 2;
    const float* src = mat ? Wd0 : Wa0;
    u16* dst = mat ? WdT : WaT;
    int nbase = nt * 64, kbase = kt * 64;
    int cl = tid & 63;
#pragma unroll
    for (int i = 0; i < 16; ++i) {
      int kl = i * 4 + (tid >> 6);
      tl[kl][cl] = f2b(src[(size_t)(kbase + kl) * 256 + nbase + cl]);
    }
    __syncthreads();
#pragma unroll
    for (int i = 0; i < 16; ++i) {
      int nl = i * 4 + (tid >> 6);
      int kl = tid & 63;
      dst[(size_t)(nbase + nl) * 512 + kbase + kl] = tl[kl][nl];
    }
  }
}

// ---------------------------------------------------------------------------
// Main persistent LSTM kernel.  256 blocks, XCD-AFFINITY MAPPING (R4):
//   stage = bid & 7 (bid%8 -> XCD), slice = bid >> 3; stages 6,7 exit early.
// SYNC (R6, kept): plain-store publish to local mirror + sc0-load poll;
//   master (MALL, agent) flags for producer check + WAR + every-8th-iter
//   fallback merge (placement safety: mirror stale-low -> master rescues).
// COMPUTE (R8): R6's simple 8-load batches (R7's manual ping-pong pipeline
//   REGRESSED -31% -> reverted; compiler schedules the simple form better).
//   NEW: stage-0 emb K-split rebalanced w2/w3 = j[0,160)/[160,320) -- 5 K-
//   slices each (was 8/2) -- and each m-tile's 10 f4v row loads issue as ONE
//   batch: 4 serialized MALL round-trips instead of 8 on the rate-setting
//   stage.  ids gathers hoisted above the flag poll (flag-independent).
// h ring layout: [slot][stage][slice-tile 0..31][row 0..63][16 units];
//   agent-scope 8B write-through stores (contiguous 2KB tile); plain cached
//   consumer loads kept fresh by ring depth 32 + staggered acquire fence
//   every 8 steps (staleness bound 8 < 32).
// out3 ALIASES WT (dead after prologue counter-barrier).
// ---------------------------------------------------------------------------
__global__ __launch_bounds__(256, 1) void lstm_main(
    const u16* __restrict__ WT, const float* __restrict__ emb,
    const int* __restrict__ ids, const float* __restrict__ bias,
    u16* __restrict__ hist, const u16* __restrict__ zbuf,
    u16* __restrict__ out3, unsigned* __restrict__ bar)
{
  __shared__ float lpart[4][48][68];   // [src wave][3 m-tiles *16][64 cols+pad]
  __shared__ __align__(16) u16 hs[64][20];  // h repack tile, padded row (40B) vs bank conflicts
  const int tid = threadIdx.x;
  const int w = tid >> 6;            // wave id (K-split, and cell-update row group)
  const int lane = tid & 63;
  const int lm = lane & 15, qk = lane >> 4;
  const int bid = blockIdx.x;
  const int stage = bid & 7;         // XCD affinity: bid%8 -> XCD
  const int slice = bid >> 3;        // 0..31
  const int u0 = slice * 16;

  // One-time barrier: all B-frag reads complete before out3 tramples WT.
  // (idle stage-slots participate, then exit)
  if (stage >= 6) {
    __syncthreads();
    if (tid == 0) {
      __hip_atomic_fetch_add(bar, 1u, __ATOMIC_RELAXED, __HIP_MEMORY_SCOPE_AGENT);
      while (__hip_atomic_load(bar, __ATOMIC_RELAXED, __HIP_MEMORY_SCOPE_AGENT) < (unsigned)NBLK)
        __builtin_amdgcn_s_sleep(2);
    }
    __syncthreads();
    return;
  }

  const int d = stage / 3, l = stage - 3 * d;

  unsigned* flags = bar + 16;                       // 6*32 master words (MALL)
  unsigned* fO = flags + stage * 32;
  unsigned* fP = flags + (l > 0 ? (stage - 1) : stage) * 32;
  unsigned* fC = flags + (l < 2 ? (stage + 1) : stage) * 32;
  unsigned* myf = fO + slice;
  unsigned* mirS = bar + 256 + stage * 32;          // per-stage LOCAL mirror (XCD L2)

  // B fragments: col = nt*512 + u0 + lm (gate nt).
  // k-range per wave: l>0 or w<2 -> k = w*256 + ks*32 (rec/k12 rows);
  // stage-0 emb waves (l==0, w>=2): k = 512 + (w-2)*160 + ks*32 (ks 0..4 used;
  // 5..7 land in the zero-padded tail rows <1024, harmless).
  const int kbase = (l == 0 && w >= 2) ? (512 + (w - 2) * 160) : (w * 256);
  s8v bfr[8][4];
#pragma unroll
  for (int ks = 0; ks < 8; ++ks)
#pragma unroll
    for (int nt = 0; nt < 4; ++nt)
      bfr[ks][nt] = *(const s8v*)(WT + ((size_t)stage * 2048 + nt * 512 + u0 + lm) * 1024
                                  + kbase + ks * 32 + qk * 8);
  float bias4[4];
#pragma unroll
  for (int nt = 0; nt < 4; ++nt)
    bias4[nt] = bias[((size_t)d * 3 + l) * 2048 + nt * 512 + u0 + lm];

  float c[4] = {0.f, 0.f, 0.f, 0.f};      // cell state, rows 16w+qk*4+r, unit u0+lm
  const int brow = 16 * w + qk * 4;
  const f4v fzero = {0.f, 0.f, 0.f, 0.f};

  // h-load addressing constants for the tiled layout:
  // element k of a row lives at tile (k>>4), elem offset row*16 + (k&15).
  const int kc = (qk & 1) * 8;               // within-tile elem of this lane's 8-elem run
  const int slq = qk >> 1;                   // tile contribution of qk

  __syncthreads();
  if (tid == 0) {
    __hip_atomic_fetch_add(bar, 1u, __ATOMIC_RELAXED, __HIP_MEMORY_SCOPE_AGENT);
    while (__hip_atomic_load(bar, __ATOMIC_RELAXED, __HIP_MEMORY_SCOPE_AGENT) < (unsigned)NBLK)
      __builtin_amdgcn_s_sleep(2);
  }
  __syncthreads();

  for (int s = 0; s < 258; ++s) {
    const int t = s - l;
    const bool act = (t >= 0 && t < 256);
    const int tx = d ? (255 - t) : t;        // time index into input sequence

    // ---- ids gathers hoisted above the poll (flag-independent; latency
    //      overlaps the barrier wait) ----
    int idv[4] = {0, 0, 0, 0};
    if (act && l == 0 && w >= 2) {
#pragma unroll
      for (int mt = 0; mt < 4; ++mt) idv[mt] = ids[(mt * 16 + lm) * 256 + tx];
    }

    // ---- dependency wait ----
    if (w == 0) {
      const unsigned sU = (unsigned)s;
      if (l < 2 && (s & 7) == 0) {
        // WAR backpressure: consumer must be within 24 steps (covers s..s+7 vs ring 32)
        for (;;) {
          bool ok = true;
          if (lane < 32) {
            int vC = (int)__hip_atomic_load(fC + lane, __ATOMIC_RELAXED, __HIP_MEMORY_SCOPE_AGENT);
            ok = (vC >= s - 24);
          }
          if (__all(ok)) break;
          __builtin_amdgcn_s_sleep(2);
        }
      }
      unsigned it = 0;
      for (;;) {
        bool ok = true;
        if (lane < 32) {
          unsigned v = ld_l2(mirS + lane);
          if (v < sU && (it & 7) == 7) {
            unsigned vm = __hip_atomic_load(fO + lane, __ATOMIC_RELAXED, __HIP_MEMORY_SCOPE_AGENT);
            if (vm > v) v = vm;
          }
          ok = (v >= sU);
        } else if (l > 0) {
          unsigned v = __hip_atomic_load(fP + (lane - 32), __ATOMIC_RELAXED, __HIP_MEMORY_SCOPE_AGENT);
          ok = (v >= sU);
        }
        if (__all(ok)) break;
        ++it;
        __builtin_amdgcn_s_sleep(1);
      }
      if (tid == 0 && ((s + stage) & 7) == 7)
        __builtin_amdgcn_fence(__ATOMIC_ACQUIRE, "agent");  // staggered inv: staleness <=8 < 32
    }
    __syncthreads();

    if (act) {
      const u16* lo;
      const u16* hi;
      if (l == 0) {
        lo = (t == 0) ? zbuf
             : hist + ((size_t)((t - 1) & (HDEPTH - 1)) * 6 + stage) * 32768;      // h1[t-1]
        hi = lo;                                                  // unused (emb path)
      } else {
        lo = hist + ((size_t)(t & (HDEPTH - 1)) * 6 + (stage - 1)) * 32768;        // h_{l-1}[t]
        hi = (t == 0) ? zbuf
             : hist + ((size_t)((t - 1) & (HDEPTH - 1)) * 6 + stage) * 32768;      // h_l[t-1]
      }

      f4v acc[4][4];
#pragma unroll
      for (int mt = 0; mt < 4; ++mt)
#pragma unroll
        for (int nt = 0; nt < 4; ++nt) acc[mt][nt] = fzero;

      if (l == 0 && w >= 2) {
        // ---- input-projection side: A = emb[ids[row][tx]], j-range
        //      [jb, jb+160) with jb = (w-2)*160; per m-tile ONE batch of 10
        //      f4v loads -> 4 serialized MALL round-trips total ----
        const int jb = (w - 2) * 160;
#pragma unroll
        for (int mt = 0; mt < 4; ++mt) {
          const float* er = emb + (size_t)idv[mt] * 300 + jb + qk * 8;
          f4v f[10];
#pragma unroll
          for (int ks = 0; ks < 4; ++ks) {
            f[2 * ks]     = *(const f4v*)(er + ks * 32);
            f[2 * ks + 1] = *(const f4v*)(er + ks * 32 + 4);
          }
          if (w == 2) {                    // ks=4: j 128..159, all valid
            f[8] = *(const f4v*)(er + 128);
            f[9] = *(const f4v*)(er + 132);
          } else {                         // ks=4: j 288..319, valid only j<300
            if (qk == 0)      { f[8] = *(const f4v*)(er + 128); f[9] = *(const f4v*)(er + 132); }
            else if (qk == 1) { f[8] = *(const f4v*)(er + 128); f[9] = fzero; }
            else              { f[8] = fzero; f[9] = fzero; }   // j>=304: WT rows zero
          }
#pragma unroll
          for (int ks = 0; ks < 5; ++ks) {
            s8v a = cvt8(f[2 * ks], f[2 * ks + 1]);
#pragma unroll
            for (int nt = 0; nt < 4; ++nt)
              acc[mt][nt] = __builtin_amdgcn_mfma_f32_16x16x32_bf16(a, bfr[ks][nt], acc[mt][nt], 0, 0, 0);
          }
        }
      } else {
        // ---- standard h-side path: batch 8 fragment loads per m-tile, then
        //      32 MFMAs (R6 structure; compiler schedules this well) ----
        const u16* aptr = (w < 2) ? lo : hi;
        const int slb = ((w & 1) * 16) + slq;      // tile index base: koff/16 + qk/2
#pragma unroll
        for (int mt = 0; mt < 4; ++mt) {
          s8v av[8];
#pragma unroll
          for (int ks = 0; ks < 8; ++ks)
            av[ks] = *(const s8v*)(aptr + (size_t)(slb + 2 * ks) * 1024 + (mt * 16 + lm) * 16 + kc);
#pragma unroll
          for (int ks = 0; ks < 8; ++ks)
#pragma unroll
            for (int nt = 0; nt < 4; ++nt)
              acc[mt][nt] = __builtin_amdgcn_mfma_f32_16x16x32_bf16(av[ks], bfr[ks][nt], acc[mt][nt], 0, 0, 0);
        }
      }

      // cross-wave K reduction: wave w keeps m-tile w, ships the other three
#pragma unroll
      for (int mt = 0; mt < 4; ++mt) {
        if (mt == w) continue;
        int slot = mt - (mt > w ? 1 : 0);
#pragma unroll
        for (int nt = 0; nt < 4; ++nt)
#pragma unroll
          for (int r = 0; r < 4; ++r)
            lpart[w][slot * 16 + qk * 4 + r][nt * 16 + lm] = acc[mt][nt][r];
      }
      __syncthreads();

      float z[4][4];
#pragma unroll
      for (int nt = 0; nt < 4; ++nt)
#pragma unroll
        for (int r = 0; r < 4; ++r) {
          float v = acc[w][nt][r];
#pragma unroll
          for (int ps = 0; ps < 4; ++ps) {
            if (ps == w) continue;
            int slot = w - (w > ps ? 1 : 0);
            v += lpart[ps][slot * 16 + qk * 4 + r][nt * 16 + lm];
          }
          z[nt][r] = v + bias4[nt];
        }

      // cell update: i,f,g,o = z[0..3]; stage h into LDS for wide stores
#pragma unroll
      for (int r = 0; r < 4; ++r) {
        float zi = z[0][r], zf = z[1][r], zg = z[2][r], zo = z[3][r];
        float si = 1.f / (1.f + __expf(-zi));
        float sf = 1.f / (1.f + __expf(-zf));
        float so = 1.f / (1.f + __expf(-zo));
        float sg = zg / (1.f + fabsf(zg));
        float cn = sf * c[r] + si * sg;
        c[r] = cn;
        float h = so * (cn / (1.f + fabsf(cn)));
        hs[brow + r][lm] = f2b(h);
      }
      __syncthreads();

      // cooperative write-through to MALL: 256 threads x 8B agent-scope stores,
      // fully contiguous 2KB tile -> 32 complete 64B lines, fast vmcnt drain.
      u16* hq = hist + ((size_t)(t & (HDEPTH - 1)) * 6 + stage) * 32768
                     + (size_t)slice * 1024;
      int row = tid >> 2, part = tid & 3;
      u64 v8 = *(const u64*)&hs[row][part * 4];
      __hip_atomic_store((u64*)(hq + tid * 4), v8, __ATOMIC_RELAXED, __HIP_MEMORY_SCOPE_AGENT);
      if (l == 2)
        *(u64*)(out3 + ((size_t)d * 256 + t) * 64 * 512
                + (size_t)row * 512 + u0 + part * 4) = v8;  // plain cached store
    }
    __syncthreads();   // drain all stores (vmcnt(0) per wave) before publishing
    if (tid == 0) {
      __hip_atomic_store(mirS + slice, (unsigned)(s + 1),
                         __ATOMIC_RELAXED, __HIP_MEMORY_SCOPE_WORKGROUP);  // plain -> local L2
      __hip_atomic_store(myf, (unsigned)(s + 1),
                         __ATOMIC_RELAXED, __HIP_MEMORY_SCOPE_AGENT);      // MALL master
    }
  }
}

// ---------------------------------------------------------------------------
// Attention scores: per t-block, enc = 0.5*(out3[0][t]+out3[1][t]) on the fly,
// a = prelu(enc@Wa0+ba0), scores[b][t] = a@Wa1 + ba1.
// ---------------------------------------------------------------------------
__global__ __launch_bounds__(256) void attn_scores(
    const u16* __restrict__ out3, const u16* __restrict__ WaT,
    const float* __restrict__ ba0, const float* __restrict__ alpha_a,
    const float* __restrict__ Wa1, const float* __restrict__ ba1,
    float* __restrict__ scores)
{
  int t = blockIdx.x, tid = threadIdx.x;
  int w = tid >> 6, lane = tid & 63, lm = lane & 15, qk = lane >> 4;
  const u16* e0 = out3 + (size_t)t * 64 * 512;
  const u16* e1 = out3 + ((size_t)256 + t) * 64 * 512;
  const f4v fzero = {0.f, 0.f, 0.f, 0.f};
  f4v acc[16];
#pragma unroll
  for (int nt = 0; nt < 16; ++nt) acc[nt] = fzero;

  for (int ks = 0; ks < 16; ++ks) {
    size_t aoff = (size_t)(16 * w + lm) * 512 + ks * 32 + qk * 8;
    s8v a0 = *(const s8v*)(e0 + aoff);
    s8v a1 = *(const s8v*)(e1 + aoff);
    s8v af;
#pragma unroll
    for (int j = 0; j < 8; ++j)
      af[j] = (short)f2b(0.5f * (b2f((u16)a0[j]) + b2f((u16)a1[j])));
#pragma unroll
    for (int nt = 0; nt < 16; ++nt) {
      s8v bf = *(const s8v*)(WaT + (size_t)(nt * 16 + lm) * 512 + ks * 32 + qk * 8);
      acc[nt] = __builtin_amdgcn_mfma_f32_16x16x32_bf16(af, bf, acc[nt], 0, 0, 0);
    }
  }

  float sums[4] = {0.f, 0.f, 0.f, 0.f};
#pragma unroll
  for (int nt = 0; nt < 16; ++nt) {
    int col = nt * 16 + lm;
    float bb = ba0[col];
    float al = alpha_a[col];
    float wv = Wa1[col];
#pragma unroll
    for (int r = 0; r < 4; ++r) {
      float v = acc[nt][r] + bb;
      v = (v >= 0.f) ? v : al * v;
      sums[r] += v * wv;
    }
  }
  float bb1 = ba1[0];
#pragma unroll
  for (int r = 0; r < 4; ++r) {
    float v = sums[r];
    v += __shfl_xor(v, 1, 16);
    v += __shfl_xor(v, 2, 16);
    v += __shfl_xor(v, 4, 16);
    v += __shfl_xor(v, 8, 16);
    if (lm == 0) {
      int b = 16 * w + qk * 4 + r;
      scores[(size_t)b * 256 + t] = v + bb1;
    }
  }
}

// ---------------------------------------------------------------------------
// Softmax over T + pooled[b][u] = sum_t w[t]*enc[b][t][u]
// ---------------------------------------------------------------------------
__global__ __launch_bounds__(256) void attn_pool(
    const u16* __restrict__ out3, const float* __restrict__ scores,
    u16* __restrict__ pooled)
{
  __shared__ float red[256];
  __shared__ float wts[256];
  int b = blockIdx.x, tid = threadIdx.x;
  float s = scores[(size_t)b * 256 + tid];
  red[tid] = s; __syncthreads();
  for (int o = 128; o > 0; o >>= 1) { if (tid < o) red[tid] = fmaxf(red[tid], red[tid + o]); __syncthreads(); }
  float m = red[0]; __syncthreads();
  float e = __expf(s - m);
  red[tid] = e; __syncthreads();
  for (int o = 128; o > 0; o >>= 1) { if (tid < o) red[tid] += red[tid + o]; __syncthreads(); }
  float inv = 1.f / red[0];
  wts[tid] = e * inv; __syncthreads();

  int u2 = tid * 2;
  float a0 = 0.f, a1 = 0.f;
#pragma unroll 4
  for (int t = 0; t < 256; ++t) {
    float wt = wts[t];
    const ushort2 v0 = *(const ushort2*)(out3 + ((size_t)t * 64 + b) * 512 + u2);
    const ushort2 v1 = *(const ushort2*)(out3 + (((size_t)256 + t) * 64 + b) * 512 + u2);
    a0 += wt * 0.5f * (b2f(v0.x) + b2f(v1.x));
    a1 += wt * 0.5f * (b2f(v0.y) + b2f(v1.y));
  }
  pooled[(size_t)b * 512 + u2] = f2b(a0);
  pooled[(size_t)b * 512 + u2 + 1] = f2b(a1);
}

// ---------------------------------------------------------------------------
// Head: h = prelu(BN(pooled@Wd0+bd0)); out = softmax(h@Wd1+bd1)  (float out)
// ---------------------------------------------------------------------------
__global__ __launch_bounds__(256) void head(
    const u16* __restrict__ pooled, const u16* __restrict__ WdT,
    const float* __restrict__ bd0, const float* __restrict__ gamma,
    const float* __restrict__ beta, const float* __restrict__ bn_mean,
    const float* __restrict__ bn_var, const float* __restrict__ alpha_h,
    const float* __restrict__ Wd1, const float* __restrict__ bd1,
    float* __restrict__ outp)
{
  __shared__ float hl[64][260];
  __shared__ float lg[64][8];
  int tid = threadIdx.x;
  int w = tid >> 6, lane = tid & 63, lm = lane & 15, qk = lane >> 4;
  const f4v fzero = {0.f, 0.f, 0.f, 0.f};
  f4v acc[16];
#pragma unroll
  for (int nt = 0; nt < 16; ++nt) acc[nt] = fzero;
  for (int ks = 0; ks < 16; ++ks) {
    s8v a = *(const s8v*)(pooled + (size_t)(16 * w + lm) * 512 + ks * 32 + qk * 8);
#pragma unroll
    for (int nt = 0; nt < 16; ++nt) {
      s8v bf = *(const s8v*)(WdT + (size_t)(nt * 16 + lm) * 512 + ks * 32 + qk * 8);
      acc[nt] = __builtin_amdgcn_mfma_f32_16x16x32_bf16(a, bf, acc[nt], 0, 0, 0);
    }
  }
#pragma unroll
  for (int nt = 0; nt < 16; ++nt) {
    int col = nt * 16 + lm;
    float mn = bn_mean[col];
    float sc = gamma[col] * rsqrtf(bn_var[col] + 1e-3f);
    float be = beta[col];
    float al = alpha_h[col];
    float b0 = bd0[col];
#pragma unroll
    for (int r = 0; r < 4; ++r) {
      float v = acc[nt][r] + b0;
      v = (v - mn) * sc + be;
      v = (v >= 0.f) ? v : al * v;
      hl[16 * w + qk * 4 + r][col] = v;
    }
  }
  __syncthreads();
  for (int idx = tid; idx < 448; idx += 256) {
    int b = idx / 7, cc = idx - b * 7;
    float sv = bd1[cc];
    for (int k = 0; k < 256; ++k) sv += hl[b][k] * Wd1[k * 7 + cc];
    lg[b][cc] = sv;
  }
  __syncthreads();
  if (tid < 64) {
    float mx = -1e30f;
#pragma unroll
    for (int cc = 0; cc < 7; ++cc) mx = fmaxf(mx, lg[tid][cc]);
    float sum = 0.f; float ex[7];
#pragma unroll
    for (int cc = 0; cc < 7; ++cc) { ex[cc] = __expf(lg[tid][cc] - mx); sum += ex[cc]; }
    float inv = 1.f / sum;
#pragma unroll
    for (int cc = 0; cc < 7; ++cc) outp[tid * 7 + cc] = ex[cc] * inv;
  }
}

// ---------------------------------------------------------------------------
extern "C" void kernel_launch(void* const* d_in, const int* in_sizes, int n_in,
                              void* d_out, int out_size, void* d_ws, size_t ws_size,
                              hipStream_t stream)
{
  (void)in_sizes; (void)n_in; (void)out_size; (void)ws_size;
  const int*   ids     = (const int*)d_in[0];
  const float* emb     = (const float*)d_in[1];
  const float* k0      = (const float*)d_in[2];
  const float* k12     = (const float*)d_in[3];
  const float* rec     = (const float*)d_in[4];
  const float* bias    = (const float*)d_in[5];
  const float* Wa0     = (const float*)d_in[6];
  const float* ba0     = (const float*)d_in[7];
  const float* alpha_a = (const float*)d_in[8];
  const float* Wa1     = (const float*)d_in[9];
  const float* ba1     = (const float*)d_in[10];
  const float* Wd0     = (const float*)d_in[11];
  const float* bd0     = (const float*)d_in[12];
  const float* gamma   = (const float*)d_in[13];
  const float* beta    = (const float*)d_in[14];
  const float* bn_mean = (const float*)d_in[15];
  const float* bn_var  = (const float*)d_in[16];
  const float* alpha_h = (const float*)d_in[17];
  const float* Wd1     = (const float*)d_in[18];
  const float* bd1     = (const float*)d_in[19];

  char* ws = (char*)d_ws;
  // out3 (33,554,432 B) ALIASES WT (25,165,824 B): WT is dead once lstm_main's
  // prologue barrier passes (B-frags register-resident); out3 writes start after.
  u16* WT      = (u16*)(ws);                    // [0, 25.17 MB)
  u16* out3    = (u16*)(ws);                    // [0, 33.55 MB)
  u16* hist    = (u16*)(ws + 33554432);         // 32*6*32*1024*2 = 12,582,912
  u16* WaT     = (u16*)(ws + 46137344);         // 262,144
  u16* WdT     = (u16*)(ws + 46399488);         // 262,144
  float* scores= (float*)(ws + 46661632);       // 65,536
  u16* pooled  = (u16*)(ws + 46727168);         // 65,536
  u16* zbuf    = (u16*)(ws + 46792704);         // 65,536 (zero tile)
  unsigned* bar= (unsigned*)(ws + 46858240);    // [0]=prologue counter, +16: 192 master
                                                // flags, +256: 192 local-mirror flags
                                                // total 46,860,288 B

  hipMemsetAsync(zbuf, 0, 65536, stream);
  hipMemsetAsync(bar, 0, 2048, stream);

  prep_weights<<<dim3(3136), dim3(256), 0, stream>>>(k0, k12, rec, Wa0, Wd0, WT, WaT, WdT);

  void* args[] = { (void*)&WT, (void*)&emb, (void*)&ids, (void*)&bias,
                   (void*)&hist, (void*)&zbuf, (void*)&out3, (void*)&bar };
  hipLaunchCooperativeKernel((void*)lstm_main, dim3(NBLK), dim3(256), args, 0, stream);

  attn_scores<<<dim3(256), dim3(256), 0, stream>>>(out3, WaT, ba0, alpha_a, Wa1, ba1, scores);
  attn_pool<<<dim3(64), dim3(256), 0, stream>>>(out3, scores, pooled);
  head<<<dim3(1), dim3(256), 0, stream>>>(pooled, WdT, bd0, gamma, beta, bn_mean, bn_var,
                                          alpha_h, Wd1, bd1, (float*)d_out);
}